// Round 10
// baseline (106.085 us; speedup 1.0000x reference)
//
#include <hip/hip_runtime.h>

#define CCH 256
#define HIDN 64
#define NB  8
#define NHW 4096

// ws layout (dwords): w1pk[16384] | w2pk[9216]  (= 100 KB)
#define W1PK_OFF 0
#define W2PK_OFF 16384

typedef __attribute__((ext_vector_type(8))) short bf16x8;
typedef __attribute__((ext_vector_type(4))) float f32x4;
typedef __attribute__((ext_vector_type(4))) int   i32x4;
typedef __attribute__((ext_vector_type(2))) int   i32x2;

__device__ __forceinline__ unsigned short bf16_rne(float f) {
    unsigned u = __float_as_uint(f);
    u += 0x7FFFu + ((u >> 16) & 1u);
    return (unsigned short)(u >> 16);
}
__device__ __forceinline__ float bf16_f32(unsigned short s) {
    return __uint_as_float(((unsigned)s) << 16);
}
__device__ __forceinline__ bf16x8 as_bf16(i32x4 v) {
    union { i32x4 i; bf16x8 b; } u; u.i = v; return u.b;
}

// ---------------------------------------------------------------------------
// Prepack weights into MFMA A-fragment order, split hi/lo bf16. (verified R8)
//   elem ei of lane l: m = mt*16 + (l&15); k = ks*32 + (ei>>2)*16 + ((l>>4)&3)*4 + (ei&3)
// w1pk dword idx = ot*4096 + ks*512 + pass*256 + lane*4 + d   (ot<4, ks<8)
// w2pk dword idx = jt*1024 + ks*512 + pass*256 + lane*4 + d   (jt<9, ks<2)
// ---------------------------------------------------------------------------
__global__ __launch_bounds__(256) void prepack_kernel(
    const float* __restrict__ w_reduce, const float* __restrict__ w_span,
    unsigned* __restrict__ ws)
{
    const int idx = blockIdx.x * 256 + threadIdx.x;   // 100*256 = 25600
    int d, lane, pass, ks, mt, K, base;
    const float* W;
    if (idx < 16384) {
        d = idx & 3; lane = (idx >> 2) & 63; pass = (idx >> 8) & 1;
        ks = (idx >> 9) & 7; mt = (idx >> 12) & 3;
        W = w_reduce; K = 256; base = W1PK_OFF + idx;
    } else {
        const int i2 = idx - 16384;
        d = i2 & 3; lane = (i2 >> 2) & 63; pass = (i2 >> 8) & 1;
        ks = (i2 >> 9) & 1; mt = i2 >> 10;
        W = w_span; K = 64; base = W2PK_OFF + i2;
    }
    const int m = mt * 16 + (lane & 15);
    const int g = (lane >> 4) & 3;
    unsigned o = 0;
    #pragma unroll
    for (int h = 0; h < 2; ++h) {
        const int ei = d * 2 + h;
        const int k  = ks * 32 + ((ei >> 2) << 4) + (g << 2) + (ei & 3);
        const float w = W[m * K + k];
        const unsigned short hi = bf16_rne(w);
        const unsigned short v  = pass ? bf16_rne(w - bf16_f32(hi)) : hi;
        o |= ((unsigned)v) << (16 * h);
    }
    ws[base] = o;
}

// ---------------------------------------------------------------------------
// Fused involution, MFMA gen. Block = 512 thr (8 waves) = HALF an image row
// (32 px). Grid = 1024 = 4 blocks/CU. LDS 31808 B, disjoint regions:
//   xT  dw[0,     4288) : [32 px][134 dw]  bf16 x (stride 134 == 6 mod 32)
//   hT  dw[4288,  5504) : [32 px][38 dw]   bf16 hid
//   kls sh[11008, 15904): [144 j][34 sh]   bf16 kmap
// ---------------------------------------------------------------------------
__global__ __launch_bounds__(512, 6) void invol_fused(
    const float* __restrict__ x,        // [B,256,64,64]
    const float* __restrict__ b_reduce, // [64]
    const float* __restrict__ b_span,   // [144]
    const unsigned* __restrict__ wpk,   // w1pk/w2pk
    float* __restrict__ out)            // [B,256,64,64]
{
    __shared__ __align__(16) int lds[7952];
    short* const lds_s = (short*)lds;

    const int tid  = threadIdx.x;
    const int lane = tid & 63;
    const int wid  = __builtin_amdgcn_readfirstlane(tid >> 6);
    const int n    = lane & 15;
    const int g    = lane >> 4;

    const int raw = blockIdx.x;                    // [0,1024)
    const int id  = ((raw & 7) << 7) | (raw >> 3); // XCD i owns image i
    const int b   = id >> 7;
    const int hr  = (id >> 1) & 63;
    const int ph  = id & 1;                        // half-row select

    const float* xb = x + (size_t)b * (CCH * NHW) + hr * 64 + ph * 32;

    // ---- stage half-row -> bf16 xT[px][c] ----
    {
        const int px = tid & 31;
        const int c0 = (tid >> 5) * 16;            // 16 channels per thread
        const float* xp = xb + (size_t)c0 * NHW + px;
        int* dst = &lds[px * 134 + (c0 >> 1)];
        int tmp[8];
        #pragma unroll
        for (int i = 0; i < 8; ++i) {
            const float f0 = xp[(2 * i) * NHW];
            const float f1 = xp[(2 * i + 1) * NHW];
            tmp[i] = (int)((unsigned)bf16_rne(f0) |
                           ((unsigned)bf16_rne(f1) << 16));
        }
        #pragma unroll
        for (int i = 0; i < 4; ++i) {              // 8B-aligned b64 writes
            const i32x2 v = {tmp[2 * i], tmp[2 * i + 1]};
            *(i32x2*)&dst[2 * i] = v;
        }
    }
    __syncthreads();

    // ---- phase 1: hid = relu(W1*x + b1); 1 MFMA tile per wave ----
    const int ot = wid >> 1;           // o-tile (4)
    const int pt = wid & 1;            // px-tile (2)
    f32x4 acc = {0.f, 0.f, 0.f, 0.f};
    const int* w1pk = (const int*)wpk + W1PK_OFF;

    #pragma unroll
    for (int ks = 0; ks < 8; ++ks) {
        const int abase = ot * 4096 + ks * 512 + lane * 4;
        const i32x4 ah = *(const i32x4*)(w1pk + abase);        // hi pass
        const i32x4 al = *(const i32x4*)(w1pk + abase + 256);  // lo pass
        const int bb = (pt * 16 + n) * 134 + ks * 16 + g * 2;
        const i32x2 p0 = *(const i32x2*)&lds[bb];
        const i32x2 p1 = *(const i32x2*)&lds[bb + 8];
        const i32x4 b0 = {p0.x, p0.y, p1.x, p1.y};
        const bf16x8 fb = as_bf16(b0);
        acc = __builtin_amdgcn_mfma_f32_16x16x32_bf16(as_bf16(ah), fb, acc, 0, 0, 0);
        acc = __builtin_amdgcn_mfma_f32_16x16x32_bf16(as_bf16(al), fb, acc, 0, 0, 0);
    }

    // ---- bias + relu -> hT[px][o] (disjoint region: no barrier needed) ----
    {
        const f32x4 br = *(const f32x4*)&b_reduce[ot * 16 + g * 4];
        const unsigned h0 = (unsigned)bf16_rne(fmaxf(acc.x + br.x, 0.f))
                          | ((unsigned)bf16_rne(fmaxf(acc.y + br.y, 0.f)) << 16);
        const unsigned h1 = (unsigned)bf16_rne(fmaxf(acc.z + br.z, 0.f))
                          | ((unsigned)bf16_rne(fmaxf(acc.w + br.w, 0.f)) << 16);
        const i32x2 hv = {(int)h0, (int)h1};
        *(i32x2*)&lds[4288 + (pt * 16 + n) * 38 + ot * 8 + g * 2] = hv;
    }
    __syncthreads();

    // ---- phase 2: kmap = W2*hid + b2 -> kls[j][px] bf16 ----
    const int* w2pk = (const int*)wpk + W2PK_OFF;
    for (int t = wid; t < 18; t += 8) {            // 9 j-tiles x 2 px-tiles
        const int jt = t >> 1, pt2 = t & 1;
        f32x4 a2 = {0.f, 0.f, 0.f, 0.f};
        #pragma unroll
        for (int ks = 0; ks < 2; ++ks) {
            const int abase = jt * 1024 + ks * 512 + lane * 4;
            const i32x4 ah = *(const i32x4*)(w2pk + abase);
            const i32x4 al = *(const i32x4*)(w2pk + abase + 256);
            const int bb = 4288 + (pt2 * 16 + n) * 38 + ks * 16 + g * 2;
            const i32x2 p0 = *(const i32x2*)&lds[bb];
            const i32x2 p1 = *(const i32x2*)&lds[bb + 8];
            const i32x4 bi = {p0.x, p0.y, p1.x, p1.y};
            const bf16x8 fb = as_bf16(bi);
            a2 = __builtin_amdgcn_mfma_f32_16x16x32_bf16(as_bf16(ah), fb, a2, 0, 0, 0);
            a2 = __builtin_amdgcn_mfma_f32_16x16x32_bf16(as_bf16(al), fb, a2, 0, 0, 0);
        }
        const f32x4 bs = *(const f32x4*)&b_span[jt * 16 + g * 4];
        const int jb = jt * 16 + g * 4;
        const int pxi = pt2 * 16 + n;
        lds_s[11008 + (jb + 0) * 34 + pxi] = (short)bf16_rne(a2.x + bs.x);
        lds_s[11008 + (jb + 1) * 34 + pxi] = (short)bf16_rne(a2.y + bs.y);
        lds_s[11008 + (jb + 2) * 34 + pxi] = (short)bf16_rne(a2.z + bs.z);
        lds_s[11008 + (jb + 3) * 34 + pxi] = (short)bf16_rne(a2.w + bs.w);
    }
    __syncthreads();

    // ---- apply: thread = (px, group); 16 channels, kv[9] in registers ----
    const int px  = lane & 31;
    const int grp = wid * 2 + (lane >> 5);         // == channel group 0..15
    const int w   = ph * 32 + px;                  // global column

    const bool vwm = (w > 0), vwp = (w < 63);
    const bool vhm = (hr > 0), vhp = (hr < 63);
    const bool vk[9] = { vhm && vwm, vhm, vhm && vwp,
                         vwm,        true, vwp,
                         vhp && vwm, vhp, vhp && vwp };
    float kv[9];
    #pragma unroll
    for (int r = 0; r < 9; ++r) {
        const float v = bf16_f32((unsigned short)
                        lds_s[11008 + (grp * 9 + r) * 34 + px]);
        kv[r] = vk[r] ? v : 0.f;
    }
    const int oWm = vwm ? -1  : 0, oWp = vwp ? 1  : 0;
    const int oHm = vhm ? -64 : 0, oHp = vhp ? 64 : 0;
    const int oo[9] = { oHm + oWm, oHm, oHm + oWp,
                        oWm,       0,   oWp,
                        oHp + oWm, oHp, oHp + oWp };

    const float* xrow = x   + (size_t)b * (CCH * NHW) + hr * 64 + w;
    float*       orow = out + (size_t)b * (CCH * NHW) + hr * 64 + w;

    #pragma unroll                                 // full unroll: static idx
    for (int m = 0; m < 16; ++m) {
        const int c = grp * 16 + m;
        const float* xc = xrow + (size_t)c * NHW;
        float a = 0.f;
        #pragma unroll
        for (int k = 0; k < 9; ++k)
            a = fmaf(xc[oo[k]], kv[k], a);
        orow[(size_t)c * NHW] = a;
    }
}

// ---------------------------------------------------------------------------
extern "C" void kernel_launch(void* const* d_in, const int* in_sizes, int n_in,
                              void* d_out, int out_size, void* d_ws, size_t ws_size,
                              hipStream_t stream) {
    const float* x        = (const float*)d_in[0];
    const float* w_reduce = (const float*)d_in[1];
    const float* b_reduce = (const float*)d_in[2];
    const float* w_span   = (const float*)d_in[3];
    const float* b_span   = (const float*)d_in[4];
    float* out = (float*)d_out;
    unsigned* ws = (unsigned*)d_ws;    // 100 KB used

    prepack_kernel<<<dim3(100), dim3(256), 0, stream>>>(w_reduce, w_span, ws);
    invol_fused<<<dim3(NB * 128), dim3(512), 0, stream>>>(
        x, b_reduce, b_span, ws, out);
}